// Round 12
// baseline (51.866 us; speedup 1.0000x reference)
//
#include <hip/hip_runtime.h>
#include <hip/hip_fp16.h>
#include <stdint.h>

// HashGridEncoder forward (Instant-NGP style), MI355X / gfx950.
// L=16 levels, T=2^15 entries/level, F=2 features, DIM=3.
//
// Round-12 restructure: rounds 5-11 (8 different inner-loop schedules,
// C-level and inline-asm, rolling lgkmcnt/vmcnt) were ALL flat at ~50us with
// every pipe <=35% busy -> the limiter is not the instruction schedule.
// OccupancyPercent 28-37% vs structural 50% exposes the real cost: LEVEL
// IMBALANCE. Coarse levels (scale 15-31) map 64 consecutive points to the
// same cell -> LDS broadcasts, near-zero conflicts, early finish; fine levels
// are fully random -> stragglers. dur == straggler time, schedule-invariant.
// Fix: each block processes a level PAIR (p, 15-p) sequentially over a
// half-chunk (kNC=32), so per-block work is balanced. Grid stays 256 (1/CU);
// staging runs twice (L3-hot, ~2us). XCD write-merge kept: bid = p*32+c ->
// bid%8 = c%8, all 8 pair-blocks of a chunk on one XCD.
// Inner loop: simplest proven form (scheduling proved perf-neutral).

constexpr int      kL  = 16;
constexpr int      kT  = 32768;           // 2^15
constexpr uint32_t kM  = kT - 1;
constexpr uint32_t kP1 = 2654435761u;
constexpr uint32_t kP2 = 805459861u;
constexpr int      kNC = 32;              // point chunks (multiple of 8)
constexpr int      kBT = 1024;            // threads per block

typedef float f32x2 __attribute__((ext_vector_type(2)));

// scales[l] = 16 * 2^(l/3) - 1  (B = 2^(1/3) exactly), f64-rounded to f32.
__device__ __constant__ float c_scales[kL] = {
    15.0f,
    19.158736798317972f,
    24.398416831491190f,
    31.0f,
    39.317473596635944f,
    49.796833662982380f,
    63.0f,
    79.634947193271890f,
    100.59366732596477f,
    127.0f,
    160.26989438654378f,
    202.18733465192953f,
    255.0f,
    321.53978877308750f,
    405.37466930385903f,
    511.0f
};

__global__ __launch_bounds__(kBT, 4) void hashgrid_fwd(
    const float*  __restrict__ x,      // (N,3)
    const float2* __restrict__ table,  // (L,T) of float2
    f32x2*        __restrict__ out,    // (N,L) of float2
    int n_points, int chunk_sz)
{
    __shared__ uint32_t ltab[kT];      // 128 KB: one level slice, packed f16x2

    int bid = blockIdx.x;
    int p   = bid >> 5;                // pair index 0..7
    int c   = bid & 31;                // chunk 0..31 -> XCD = c%8

    int tid  = (int)threadIdx.x;
    int base = c * chunk_sz;
    int lim  = min(base + chunk_sz, n_points);

#pragma unroll
    for (int phase = 0; phase < 2; ++phase) {
        int l = (phase == 0) ? p : (kL - 1 - p);   // coarse + fine pair

        // all waves must be done READING the previous slice before overwrite
        __syncthreads();

        // ---- stage level slice: 32768 f32x2 -> packed f16x2 ----
        const float4* tsrc4 = reinterpret_cast<const float4*>(table + (size_t)l * kT);
        for (int e = tid; e < kT / 2; e += kBT) {
            float4 q = tsrc4[e];
            uint2 pp;
            pp.x = ((uint32_t)__half_as_ushort(__float2half_rn(q.y)) << 16)
                 |  (uint32_t)__half_as_ushort(__float2half_rn(q.x));
            pp.y = ((uint32_t)__half_as_ushort(__float2half_rn(q.w)) << 16)
                 |  (uint32_t)__half_as_ushort(__float2half_rn(q.z));
            *reinterpret_cast<uint2*>(&ltab[e * 2]) = pp;
        }
        __syncthreads();

        float s = c_scales[l];
        float A = s * 0.5f;
        float C = fmaf(s, 0.5f, 0.5f);

        for (int n = base + tid; n < lim; n += kBT) {
            float x0 = x[n * 3 + 0];
            float x1 = x[n * 3 + 1];
            float x2 = x[n * 3 + 2];

            float p0 = fmaf(x0, A, C);
            float p1 = fmaf(x1, A, C);
            float p2 = fmaf(x2, A, C);

            float fl0 = floorf(p0), fl1 = floorf(p1), fl2 = floorf(p2);
            float fr0 = p0 - fl0,   fr1 = p1 - fl1,   fr2 = p2 - fl2;

            uint32_t g0 = (uint32_t)(int)fl0;
            uint32_t g1 = (uint32_t)(int)fl1;
            uint32_t g2 = (uint32_t)(int)fl2;

            uint32_t g0p = g0 + 1u;
            uint32_t hy0 = g1 * kP1;  uint32_t hy1 = hy0 + kP1;
            uint32_t hz0 = g2 * kP2;  uint32_t hz1 = hz0 + kP2;

            uint32_t hyz0 = hy0 ^ hz0;
            uint32_t hyz1 = hy1 ^ hz0;
            uint32_t hyz2 = hy0 ^ hz1;
            uint32_t hyz3 = hy1 ^ hz1;

            uint32_t e0 = ltab[(g0  ^ hyz0) & kM];
            uint32_t e1 = ltab[(g0p ^ hyz0) & kM];
            uint32_t e2 = ltab[(g0  ^ hyz1) & kM];
            uint32_t e3 = ltab[(g0p ^ hyz1) & kM];
            uint32_t e4 = ltab[(g0  ^ hyz2) & kM];
            uint32_t e5 = ltab[(g0p ^ hyz2) & kM];
            uint32_t e6 = ltab[(g0  ^ hyz3) & kM];
            uint32_t e7 = ltab[(g0p ^ hyz3) & kM];

            float wx0 = 1.0f - fr0;
            float wy0 = 1.0f - fr1;
            float wz0 = 1.0f - fr2;
            float wyz0 = wy0 * wz0;
            float wyz1 = fr1 * wz0;
            float wyz2 = wy0 * fr2;
            float wyz3 = fr1 * fr2;

            float acc_x = 0.0f, acc_y = 0.0f;
            const uint32_t ee[8] = {e0, e1, e2, e3, e4, e5, e6, e7};
            const float    wf[8] = {wx0 * wyz0, fr0 * wyz0,
                                    wx0 * wyz1, fr0 * wyz1,
                                    wx0 * wyz2, fr0 * wyz2,
                                    wx0 * wyz3, fr0 * wyz3};
#pragma unroll
            for (int cc = 0; cc < 8; ++cc) {
                __half2 h = *reinterpret_cast<const __half2*>(&ee[cc]);
                acc_x = fmaf(wf[cc], __low2float(h),  acc_x);
                acc_y = fmaf(wf[cc], __high2float(h), acc_y);
            }

            f32x2 r; r.x = acc_x; r.y = acc_y;
            out[(size_t)n * kL + l] = r;    // 8B @128B stride; merges in XCD L2
        }
    }
}

extern "C" void kernel_launch(void* const* d_in, const int* in_sizes, int n_in,
                              void* d_out, int out_size, void* d_ws, size_t ws_size,
                              hipStream_t stream) {
    const float*  x     = (const float*)d_in[0];
    const float2* table = (const float2*)d_in[1];
    f32x2*        out   = (f32x2*)d_out;

    int n_points = in_sizes[0] / 3;                  // (N,3) flat
    int chunk_sz = (n_points + kNC - 1) / kNC;       // 15625 for N=500000
    int blocks   = (kL / 2) * kNC;                   // 8 pairs x 32 chunks = 256

    hashgrid_fwd<<<blocks, kBT, 0, stream>>>(x, table, out, n_points, chunk_sz);
}

// Round 13
// 49.091 us; speedup vs baseline: 1.0565x; 1.0565x over previous
//
#include <hip/hip_runtime.h>
#include <hip/hip_fp16.h>
#include <stdint.h>

// HashGridEncoder forward (Instant-NGP style), MI355X / gfx950.
// L=16 levels, T=2^15 entries/level, F=2 features, DIM=3.
//
// Round-13: rounds 5-12 (9 schedules/structures) were ALL ~50us with every
// SQ-side pipe <=35% busy -> limiter is downstream: XCD-L2 TRANSACTION COUNT.
// The 8B out-store at 128B stride = 64 distinct-line txns per wave store
// (~1M txns/XCD = ~26us of the 16-channel L2 write path); round-1's 150us is
// the same model on the gather side (8M txns/XCD). Fix + decisive test:
//   kernel1: store the (already-f16) accumulator to ws[l][n] -> coalesced
//            full-line writes (62K txns/XCD instead of 1M).
//   kernel2: LDS tile-transpose [64 pts x 16 lvls] -> unpack f16->f32 ->
//            full 128B out-line writes. Pure BW (~128MB, L2/L3-resident).
// Fallback to direct f32 stores if ws_size < L*N*4 bytes.

constexpr int      kL  = 16;
constexpr int      kT  = 32768;           // 2^15
constexpr uint32_t kM  = kT - 1;
constexpr uint32_t kP1 = 2654435761u;
constexpr uint32_t kP2 = 805459861u;
constexpr int      kNC = 16;              // point chunks (multiple of 8)
constexpr int      kBT = 1024;            // threads per block

typedef float f32x2 __attribute__((ext_vector_type(2)));

// scales[l] = 16 * 2^(l/3) - 1  (B = 2^(1/3) exactly), f64-rounded to f32.
__device__ __constant__ float c_scales[kL] = {
    15.0f,
    19.158736798317972f,
    24.398416831491190f,
    31.0f,
    39.317473596635944f,
    49.796833662982380f,
    63.0f,
    79.634947193271890f,
    100.59366732596477f,
    127.0f,
    160.26989438654378f,
    202.18733465192953f,
    255.0f,
    321.53978877308750f,
    405.37466930385903f,
    511.0f
};

// ---------------- kernel 1: per-level gather, coalesced f16x2 store --------
template<bool USE_WS>
__global__ __launch_bounds__(kBT, 4) void hashgrid_lvl(
    const float*  __restrict__ x,      // (N,3)
    const float2* __restrict__ table,  // (L,T) of float2
    uint32_t*     __restrict__ ws,     // [L][N] packed f16x2   (USE_WS)
    f32x2*        __restrict__ out,    // (N,L) of float2       (!USE_WS)
    int n_points, int chunk_sz)
{
    __shared__ uint32_t ltab[kT];      // 128 KB: level slice, packed f16x2

    int bid = blockIdx.x;
    int l   = bid >> 4;                // bid = l*16 + c
    int c   = bid & 15;                // -> XCD = c%8 (fallback write-merge)

    int tid  = (int)threadIdx.x;
    int base = c * chunk_sz;
    int lim  = min(base + chunk_sz, n_points);

    // ---- stage level slice: 32768 f32x2 -> packed f16x2 ----
    const float4* tsrc4 = reinterpret_cast<const float4*>(table + (size_t)l * kT);
    for (int e = tid; e < kT / 2; e += kBT) {
        float4 q = tsrc4[e];
        uint2 pp;
        pp.x = ((uint32_t)__half_as_ushort(__float2half_rn(q.y)) << 16)
             |  (uint32_t)__half_as_ushort(__float2half_rn(q.x));
        pp.y = ((uint32_t)__half_as_ushort(__float2half_rn(q.w)) << 16)
             |  (uint32_t)__half_as_ushort(__float2half_rn(q.z));
        *reinterpret_cast<uint2*>(&ltab[e * 2]) = pp;
    }
    __syncthreads();

    float s = c_scales[l];
    float A = s * 0.5f;
    float C = fmaf(s, 0.5f, 0.5f);

    for (int n = base + tid; n < lim; n += kBT) {
        float x0 = x[n * 3 + 0];
        float x1 = x[n * 3 + 1];
        float x2 = x[n * 3 + 2];

        float p0 = fmaf(x0, A, C);
        float p1 = fmaf(x1, A, C);
        float p2 = fmaf(x2, A, C);

        float fl0 = floorf(p0), fl1 = floorf(p1), fl2 = floorf(p2);
        float fr0 = p0 - fl0,   fr1 = p1 - fl1,   fr2 = p2 - fl2;

        uint32_t g0 = (uint32_t)(int)fl0;
        uint32_t g1 = (uint32_t)(int)fl1;
        uint32_t g2 = (uint32_t)(int)fl2;

        uint32_t g0p = g0 + 1u;
        uint32_t hy0 = g1 * kP1;  uint32_t hy1 = hy0 + kP1;
        uint32_t hz0 = g2 * kP2;  uint32_t hz1 = hz0 + kP2;

        uint32_t hyz0 = hy0 ^ hz0;
        uint32_t hyz1 = hy1 ^ hz0;
        uint32_t hyz2 = hy0 ^ hz1;
        uint32_t hyz3 = hy1 ^ hz1;

        uint32_t ee[8];
        ee[0] = ltab[(g0  ^ hyz0) & kM];
        ee[1] = ltab[(g0p ^ hyz0) & kM];
        ee[2] = ltab[(g0  ^ hyz1) & kM];
        ee[3] = ltab[(g0p ^ hyz1) & kM];
        ee[4] = ltab[(g0  ^ hyz2) & kM];
        ee[5] = ltab[(g0p ^ hyz2) & kM];
        ee[6] = ltab[(g0  ^ hyz3) & kM];
        ee[7] = ltab[(g0p ^ hyz3) & kM];

        float wx0 = 1.0f - fr0;
        float wy0 = 1.0f - fr1;
        float wz0 = 1.0f - fr2;
        float wyz0 = wy0 * wz0;
        float wyz1 = fr1 * wz0;
        float wyz2 = wy0 * fr2;
        float wyz3 = fr1 * fr2;
        const float wf[8] = {wx0 * wyz0, fr0 * wyz0,
                             wx0 * wyz1, fr0 * wyz1,
                             wx0 * wyz2, fr0 * wyz2,
                             wx0 * wyz3, fr0 * wyz3};

        __half2 acc = __float2half2_rn(0.0f);
#pragma unroll
        for (int cc = 0; cc < 8; ++cc) {
            __half2 h = *reinterpret_cast<const __half2*>(&ee[cc]);
            acc = __hfma2(__float2half2_rn(wf[cc]), h, acc);
        }

        if (USE_WS) {
            // coalesced 4B store: packed f16x2 (acc is already f16 — no new
            // rounding vs the round-5..12 path)
            ws[(size_t)l * n_points + n] = *reinterpret_cast<uint32_t*>(&acc);
        } else {
            f32x2 r;
            r.x = __low2float(acc);
            r.y = __high2float(acc);
            out[(size_t)n * kL + l] = r;   // scattered 8B (legacy path)
        }
    }
}

// ---------------- kernel 2: [L][N] f16x2 -> [N][L] f32x2 tile transpose ----
__global__ __launch_bounds__(256) void transpose_out(
    const uint32_t* __restrict__ ws,   // [L][N] packed f16x2
    float*          __restrict__ out,  // (N, 32) f32
    int n_points, int n_tiles)
{
    __shared__ uint32_t tile[64][kL + 1];   // +1 pad: conflict-free columns

    for (int t = blockIdx.x; t < n_tiles; t += gridDim.x) {
        int n0 = t * 64;

        int p  = (int)threadIdx.x & 63;
        int lb = (int)threadIdx.x >> 6;          // 0..3
#pragma unroll
        for (int r = 0; r < 4; ++r) {
            int l = r * 4 + lb;
            int n = min(n0 + p, n_points - 1);
            tile[p][l] = ws[(size_t)l * n_points + n];
        }
        __syncthreads();

        int p2 = (int)threadIdx.x >> 2;          // 0..63
        int j  = (int)threadIdx.x & 3;           // 0..3 -> levels 4j..4j+3
        int n  = n0 + p2;
        if (n < n_points) {
            uint32_t u0 = tile[p2][4 * j + 0];
            uint32_t u1 = tile[p2][4 * j + 1];
            uint32_t u2 = tile[p2][4 * j + 2];
            uint32_t u3 = tile[p2][4 * j + 3];
            __half2 h0 = *reinterpret_cast<__half2*>(&u0);
            __half2 h1 = *reinterpret_cast<__half2*>(&u1);
            __half2 h2 = *reinterpret_cast<__half2*>(&u2);
            __half2 h3 = *reinterpret_cast<__half2*>(&u3);
            float4 v0, v1;
            v0.x = __low2float(h0);  v0.y = __high2float(h0);
            v0.z = __low2float(h1);  v0.w = __high2float(h1);
            v1.x = __low2float(h2);  v1.y = __high2float(h2);
            v1.z = __low2float(h3);  v1.w = __high2float(h3);
            float* dst = out + (size_t)n * 32 + j * 8;
            *reinterpret_cast<float4*>(dst)     = v0;
            *reinterpret_cast<float4*>(dst + 4) = v1;
        }
        __syncthreads();
    }
}

extern "C" void kernel_launch(void* const* d_in, const int* in_sizes, int n_in,
                              void* d_out, int out_size, void* d_ws, size_t ws_size,
                              hipStream_t stream) {
    const float*  x     = (const float*)d_in[0];
    const float2* table = (const float2*)d_in[1];

    int n_points = in_sizes[0] / 3;                  // (N,3) flat
    int chunk_sz = (n_points + kNC - 1) / kNC;       // 31250 for N=500000
    int blocks   = kL * kNC;                         // 256 = 1 per CU

    size_t ws_needed = (size_t)kL * n_points * sizeof(uint32_t);   // 32MB

    if (ws_size >= ws_needed) {
        uint32_t* ws = (uint32_t*)d_ws;
        hashgrid_lvl<true><<<blocks, kBT, 0, stream>>>(
            x, table, ws, nullptr, n_points, chunk_sz);
        int n_tiles = (n_points + 63) / 64;
        int g2 = n_tiles < 2048 ? n_tiles : 2048;
        transpose_out<<<g2, 256, 0, stream>>>(
            ws, (float*)d_out, n_points, n_tiles);
    } else {
        hashgrid_lvl<false><<<blocks, kBT, 0, stream>>>(
            x, table, nullptr, (f32x2*)d_out, n_points, chunk_sz);
    }
}